// Round 4
// baseline (194.992 us; speedup 1.0000x reference)
//
#include <hip/hip_runtime.h>
#include <cstdint>
#include <cstddef>

#define NPTS 8192
#define NUM_CLASSES 5
#define XCOLS 10          // 3 coords + batch + feat + 5 seg
#define EPS2 225.0f
#define MIN_PTS 5
#define NGROUPS 10
#define BIGC 0x3fffffff
#define ECAP 1000000      // edge capacity (expected ~54k)

#define RT_ROWS 1024      // rows per k_adj block
#define JT 128            // cols (j-points) staged per k_adj block
#define RPT 4             // rows per thread

// ---------------- setup: pack coords+p2, group, init deg/ecnt ----------------
__global__ void k_setup(const float* __restrict__ x, float4* __restrict__ q,
                        int* __restrict__ grp, int* __restrict__ deg,
                        unsigned int* __restrict__ ecnt) {
    int i = blockIdx.x * blockDim.x + threadIdx.x;
    if (i == 0) *ecnt = 0u;
    if (i >= NPTS) return;
    const float* r = x + (size_t)i * XCOLS;
    float px = r[0], py = r[1], pz = r[2];
    int b = (int)r[3];
    float best = r[5]; int bc = 0;
    #pragma unroll
    for (int c = 1; c < NUM_CLASSES; c++) {
        float v = r[5 + c];
        if (v > best) { best = v; bc = c; }   // strict > keeps first max (jnp.argmax)
    }
    q[i] = make_float4(px, py, pz, px*px + py*py + pz*pz);
    grp[i] = b * NUM_CLASSES + bc;
    deg[i] = 1;          // self-adjacency (d2=0 < EPS2, same group)
}

// ---------------- adjacency -> packed edge list (g<<26|u<<13|v, j>i) + degree ----
// grid = 8 row-tiles x 64 col-slices; block = 256 threads; thread owns 4 rows.
__global__ void __launch_bounds__(256) k_adj(
        const float4* __restrict__ q, const int* __restrict__ grp,
        unsigned int* __restrict__ edges, unsigned int* __restrict__ ecnt,
        int* __restrict__ deg) {
    int rt = blockIdx.x >> 6;        // 0..7
    int cs = blockIdx.x & 63;        // 0..63
    int i0 = rt * RT_ROWS;
    int j0 = cs * JT;
    if (j0 + JT - 1 <= i0) return;   // strictly lower-triangle block: no j>i

    __shared__ float4 qs[JT];
    __shared__ int    gs[JT];
    int tid = threadIdx.x;
    if (tid < JT) { qs[tid] = q[j0 + tid]; gs[tid] = grp[j0 + tid]; }
    __syncthreads();

    int lane = tid & 63;
    float4 qi[RPT]; int gi[RPT]; int irow[RPT];
    #pragma unroll
    for (int r = 0; r < RPT; r++) {
        irow[r] = i0 + tid + 256 * r;
        qi[r] = q[irow[r]];
        gi[r] = grp[irow[r]];
    }

    #pragma unroll
    for (int w = 0; w < JT / 64; w++) {
        int jbase = j0 + w * 64;
        unsigned int lo[RPT], hi[RPT];
        #pragma unroll
        for (int r = 0; r < RPT; r++) { lo[r] = 0u; hi[r] = 0u; }
        #pragma unroll
        for (int t = 0; t < 32; t++) {
            float4 qj = qs[w * 64 + t]; int gj = gs[w * 64 + t];   // broadcast
            #pragma unroll
            for (int r = 0; r < RPT; r++) {
                float d2 = qi[r].w + qj.w - 2.0f * (qi[r].x*qj.x + qi[r].y*qj.y + qi[r].z*qj.z);
                bool a = (gi[r] == gj) && (d2 < EPS2);
                lo[r] |= a ? (1u << t) : 0u;
            }
        }
        #pragma unroll
        for (int t = 0; t < 32; t++) {
            float4 qj = qs[w * 64 + 32 + t]; int gj = gs[w * 64 + 32 + t];
            #pragma unroll
            for (int r = 0; r < RPT; r++) {
                float d2 = qi[r].w + qj.w - 2.0f * (qi[r].x*qj.x + qi[r].y*qj.y + qi[r].z*qj.z);
                bool a = (gi[r] == gj) && (d2 < EPS2);
                hi[r] |= a ? (1u << t) : 0u;
            }
        }
        unsigned long long bits[RPT]; int rowc[RPT]; int cnt = 0;
        #pragma unroll
        for (int r = 0; r < RPT; r++) {
            unsigned long long b = ((unsigned long long)hi[r] << 32) | (unsigned long long)lo[r];
            int d = irow[r] - jbase;
            unsigned long long m;
            if (d < 0) m = ~0ull;
            else if (d >= 63) m = 0ull;
            else m = ~((2ull << d) - 1ull);
            b &= m;
            bits[r] = b;
            rowc[r] = __popcll(b);
            cnt += rowc[r];
        }
        // wave-aggregated append
        int off = cnt;
        #pragma unroll
        for (int dd = 1; dd < 64; dd <<= 1) {
            int o = __shfl_up(off, dd);
            if (lane >= dd) off += o;
        }
        int tot = __shfl(off, 63);
        int excl = off - cnt;
        int base = 0;
        if (tot > 0) {
            if (lane == 63) base = (int)atomicAdd(ecnt, (unsigned int)tot);
            base = __shfl(base, 63);
        }
        int p = base + excl;
        #pragma unroll
        for (int r = 0; r < RPT; r++) {
            if (rowc[r] > 0) {
                atomicAdd(&deg[irow[r]], rowc[r]);
                unsigned int gtag = (unsigned int)gi[r] << 26;
                unsigned long long b = bits[r];
                while (b) {
                    int bb = __ffsll((unsigned long long)b) - 1;
                    b &= b - 1;
                    int j = jbase + bb;
                    if (p < ECAP) edges[p] = gtag | ((unsigned int)irow[r] << 13) | (unsigned int)j;
                    p++;
                    atomicAdd(&deg[j], 1);
                }
            }
        }
    }
}

// ---------------- LDS union-find find (path halving, lock-free) ----------------
__device__ __forceinline__ int lfind(volatile int* p, int x) {
    while (true) {
        int px = p[x];
        if (px == x) return x;
        int pp = p[px];
        if (pp == px) return px;
        p[x] = pp;            // monotone-decreasing ancestor: race-safe
        x = pp;
    }
}

// ---------------- per-group: union + rank + border + final, one block/group ----
__global__ void __launch_bounds__(1024) k_group(
        const unsigned int* __restrict__ edges, const unsigned int* __restrict__ ecnt,
        const int* __restrict__ deg, const int* __restrict__ grp,
        const float* __restrict__ x, float* __restrict__ out) {
    __shared__ int spar[NPTS];                      // parent -> later ccid (32 KB)
    __shared__ int scid[NPTS];                      // cid of reps (32 KB)
    __shared__ int lbmin[NPTS];                     // border min cid (32 KB)
    __shared__ unsigned char sgrp[NPTS];            // 8 KB
    __shared__ unsigned long long corebm[NPTS/64];  // 1 KB
    int g = blockIdx.x;
    int tid = threadIdx.x;
    unsigned int Eu = *ecnt;
    int E = (Eu > (unsigned)ECAP) ? ECAP : (int)Eu;

    for (int i = tid; i < NPTS; i += 1024) {
        spar[i] = i; sgrp[i] = (unsigned char)grp[i]; lbmin[i] = BIGC;
    }
    for (int w = tid; w < NPTS/64; w += 1024) corebm[w] = 0ull;
    __syncthreads();
    for (int i = tid; i < NPTS; i += 1024)
        if (deg[i] >= MIN_PTS) atomicOr(&corebm[i >> 6], 1ull << (i & 63));
    __syncthreads();

    auto corebit = [&](int v) -> bool { return (corebm[v >> 6] >> (v & 63)) & 1ull; };

    // union pass over this group's core-core edges
    for (int e = tid; e < E; e += 1024) {
        unsigned int pk = edges[e];
        if ((int)(pk >> 26) != g) continue;
        int u = (int)((pk >> 13) & 8191u), v = (int)(pk & 8191u);
        if (!corebit(u) || !corebit(v)) continue;
        u = lfind(spar, u); v = lfind(spar, v);
        while (u != v) {
            int big = u > v ? u : v;
            int sml = u + v - big;
            int old = atomicCAS(&spar[big], big, sml);
            if (old == big) break;
            u = lfind(spar, old); v = lfind(spar, sml);
        }
    }
    __syncthreads();
    // flatten core nodes (in place: monotone, race-safe)
    for (int i = tid; i < NPTS; i += 1024)
        if (corebit(i)) spar[i] = lfind(spar, i);
    __syncthreads();
    // rank reps of this group by index: wave 0 serial ballot scan
    if (tid < 64) {
        int lane = tid, running = 0;
        for (int w = 0; w < NPTS / 64; w++) {
            int j = w * 64 + lane;
            bool isr = corebit(j) && (spar[j] == j) && ((int)sgrp[j] == g);
            unsigned long long mask = __ballot(isr);
            if (isr) scid[j] = running + __popcll(mask & ((1ull << lane) - 1ull));
            running += __popcll(mask);
        }
    }
    __syncthreads();
    // ccid per node -> overwrite spar (read all, barrier, write all)
    int cc[NPTS / 1024];
    #pragma unroll
    for (int k = 0; k < NPTS / 1024; k++) {
        int i = tid + k * 1024;
        cc[k] = corebit(i) ? scid[spar[i]] : BIGC;
    }
    __syncthreads();
    #pragma unroll
    for (int k = 0; k < NPTS / 1024; k++) spar[tid + k * 1024] = cc[k];
    __syncthreads();
    // border pass: min core-neighbor cid (within group)
    for (int e = tid; e < E; e += 1024) {
        unsigned int pk = edges[e];
        if ((int)(pk >> 26) != g) continue;
        int u = (int)((pk >> 13) & 8191u), v = (int)(pk & 8191u);
        int cu = spar[u], cv = spar[v];
        if (cu == BIGC && cv != BIGC) atomicMin(&lbmin[u], cv);
        if (cv == BIGC && cu != BIGC) atomicMin(&lbmin[v], cu);
    }
    __syncthreads();
    // final labels + clustered output for this group's nodes
    for (int i = tid; i < NPTS; i += 1024) {
        if ((int)sgrp[i] != g) continue;
        int c = spar[i];
        int lbl = (c != BIGC) ? c : ((lbmin[i] < BIGC) ? lbmin[i] : -1);
        out[i] = (float)lbl;
        const float* r = x + (size_t)i * XCOLS;
        float* o = out + NPTS + (size_t)i * 5;
        bool keep = lbl >= 0;
        #pragma unroll
        for (int c5 = 0; c5 < 5; c5++) o[c5] = keep ? r[c5] : 0.0f;
    }
}

extern "C" void kernel_launch(void* const* d_in, const int* in_sizes, int n_in,
                              void* d_out, int out_size, void* d_ws, size_t ws_size,
                              hipStream_t stream) {
    const float* x = (const float*)d_in[0];
    float* out = (float*)d_out;
    char* ws = (char*)d_ws;

    // workspace layout (~4.2 MB)
    float4* q          = (float4*)(ws);                  // 131072 B
    int* grp           = (int*)(ws + 131072);            // 32768
    int* deg           = (int*)(ws + 163840);            // 32768
    unsigned int* ecnt = (unsigned int*)(ws + 196608);   // 256
    unsigned int* edges= (unsigned int*)(ws + 196864);   // 4 MB

    k_setup <<<NPTS / 256, 256, 0, stream>>>(x, q, grp, deg, ecnt);
    k_adj   <<<8 * 64, 256, 0, stream>>>(q, grp, edges, ecnt, deg);
    k_group <<<NGROUPS, 1024, 0, stream>>>(edges, ecnt, deg, grp, x, out);
}